// Round 3
// baseline (385.727 us; speedup 1.0000x reference)
//
#include <hip/hip_runtime.h>
#include <hip/hip_cooperative_groups.h>
#include <math.h>

namespace cg = cooperative_groups;

// Problem constants
static constexpr int Bn   = 32;
static constexpr int Tn   = 512;
static constexpr int Cn   = 128;
static constexpr int NLAG = 57;   // lags 8..64 inclusive
static constexpr int CYC  = 64;   // CYC_MAX

// ---------------------------------------------------------------------------
// Wave-parallel top-(kk+1) argmax over r_ws[b] (57 lags). lane = 0..63.
// Matches lax.top_k tie-break (smallest index wins on equal values).
// ---------------------------------------------------------------------------
__device__ __forceinline__ int topk_p(const float* __restrict__ rb,
                                      int lane, int kk) {
  float v  = (lane < NLAG) ? rb[lane] : -INFINITY;
  int  idx = lane;
  int  lag = 8;
#pragma unroll
  for (int k = 0; k < 3; ++k) {
    if (k > kk) break;
    float bv = v; int bi = idx;
#pragma unroll
    for (int m = 32; m > 0; m >>= 1) {
      const float ov = __shfl_xor(bv, m, 64);
      const int   oi = __shfl_xor(bi, m, 64);
      if (ov > bv || (ov == bv && oi < bi)) { bv = ov; bi = oi; }
    }
    lag = bi + 8;
    if (idx == bi) v = -INFINITY;
  }
  return lag;
}

// ---------------------------------------------------------------------------
// Conv unit body (dw + pw + GN + gelu + gate) for one (n, og). 256 threads.
// smem: u-view [64][129] then h1-view [128][65]. Leading syncthreads guards
// smem reuse across successive calls / phases.
// ---------------------------------------------------------------------------
__device__ __forceinline__ void conv_unit(
    int n, int og, int tid,
    const float* __restrict__ u, const float* __restrict__ Wdw,
    const float* __restrict__ Wpw, const float* __restrict__ gnw,
    const float* __restrict__ gnb, const float* __restrict__ Wgate,
    float* __restrict__ hh, float* smem, float* ubar_s) {
  const int l  = tid & 63;
  const int wq = __builtin_amdgcn_readfirstlane(tid >> 6);

  __syncthreads();   // previous users of smem done

  // stage u[n] (32KB): float4 global loads, scalar LDS writes into pad-129
  {
    const float4* u4 = (const float4*)(u + (size_t)n * CYC * Cn);
#pragma unroll
    for (int i = 0; i < 8; ++i) {
      const int idx4 = i * 256 + tid;      // 0..2047
      const float4 v = u4[idx4];
      const int ll = idx4 >> 5;
      const int cc = (idx4 & 31) << 2;
      float* d = smem + ll * 129 + cc;
      d[0] = v.x; d[1] = v.y; d[2] = v.z; d[3] = v.w;
    }
  }
  __syncthreads();

  // ubar[c] = mean over l (threads 0..127); stride-129 columns conflict-free
  if (tid < Cn) {
    float s = 0.f;
    for (int ll = 0; ll < CYC; ++ll) s += smem[ll * 129 + tid];
    ubar_s[tid] = s * (1.0f / CYC);
  }

  // depthwise conv -> registers: thread (l, wq) covers c = wq*32 .. +32
  float hreg[32];
  {
    const int c0 = wq * 32;
#pragma unroll
    for (int i = 0; i < 32; ++i) {
      const int c = c0 + i;
      float s = 0.f;
#pragma unroll
      for (int k = 0; k < 9; ++k) {
        const int ll = l + k - 4;
        if (ll >= 0 && ll < CYC) s += smem[ll * 129 + c] * Wdw[c * 9 + k];
      }
      hreg[i] = s;
    }
  }
  __syncthreads();   // all su reads done; ubar_s visible

  // gates: each wave computes its own 4 outputs; 16 lane-groups x 8 channels
  float gi[4];
  {
    const int ol   = l & 3;
    const int part = l >> 2;               // 0..15
    const int o    = og * 16 + wq * 4 + ol;
    float z = 0.f;
    const float* wg = Wgate + (size_t)o * Cn + part * 8;
    const float* ub = ubar_s + part * 8;
#pragma unroll
    for (int cc = 0; cc < 8; ++cc) z += wg[cc] * ub[cc];
    z += __shfl_xor(z, 4, 64);
    z += __shfl_xor(z, 8, 64);
    z += __shfl_xor(z, 16, 64);
    z += __shfl_xor(z, 32, 64);
    const float sig = 1.0f / (1.0f + expf(-z));
#pragma unroll
    for (int i = 0; i < 4; ++i) gi[i] = __shfl(sig, i, 64);
  }

  // overwrite LDS with h1-view [c][65]
  {
    const int c0 = wq * 32;
#pragma unroll
    for (int i = 0; i < 32; ++i) smem[(c0 + i) * 65 + l] = hreg[i];
  }
  __syncthreads();

  // pointwise: 4 outputs per wave
  const int o4 = og * 16 + wq * 4;
  float acc[4];
#pragma unroll
  for (int i = 0; i < 4; ++i) acc[i] = 0.f;
  const float* wb = Wpw + (size_t)o4 * Cn;
  for (int c = 0; c < Cn; ++c) {
    const float hv = smem[c * 65 + l];
#pragma unroll
    for (int i = 0; i < 4; ++i) acc[i] = fmaf(wb[i * Cn + c], hv, acc[i]);
  }

  // GroupNorm: this wave's 4 o == exactly one GN group (4 ch x 64 l)
  float s1 = acc[0] + acc[1] + acc[2] + acc[3];
  float s2 = acc[0]*acc[0] + acc[1]*acc[1] + acc[2]*acc[2] + acc[3]*acc[3];
#pragma unroll
  for (int m = 32; m > 0; m >>= 1) {
    s1 += __shfl_xor(s1, m, 64);
    s2 += __shfl_xor(s2, m, 64);
  }
  const float mean = s1 * (1.0f / 256.0f);
  const float var  = s2 * (1.0f / 256.0f) - mean * mean;
  const float rstd = rsqrtf(var + 1e-5f);

  float4 res;
  float* rp = (float*)&res;
#pragma unroll
  for (int i = 0; i < 4; ++i) {
    const int o = o4 + i;
    float h = (acc[i] - mean) * rstd;
    h = h * gnw[o] + gnb[o];
    h = 0.5f * h * (1.0f + erff(h * 0.70710678118654752440f));
    rp[i] = h * gi[i];
  }
  *(float4*)(hh + (size_t)n * CYC * Cn + (size_t)l * Cn + o4) = res;
}

// ---------------------------------------------------------------------------
// MEGA kernel: all 4 phases, 512 blocks x 256 threads, cooperative.
// XCD-local pipeline: XCD k (ws in [64k, 64k+64)) owns b in [4k, 4k+4)
// through every phase -> intermediates stay in that XCD's L2.
// ---------------------------------------------------------------------------
__global__ __launch_bounds__(256, 2) void mega(
    const float* __restrict__ x, const float* __restrict__ Wdw,
    const float* __restrict__ Wpw, const float* __restrict__ gnw,
    const float* __restrict__ gnb, const float* __restrict__ Wgate,
    const float* __restrict__ gamma, float* __restrict__ r_ws,
    float* __restrict__ u, float* __restrict__ hh, float* __restrict__ out) {
  cg::grid_group grid = cg::this_grid();
  const int bid = blockIdx.x;
  const int ws  = (bid & 7) * 64 + (bid >> 3);   // bijective 0..511
  const int xcd = ws >> 6;
  const int tid = threadIdx.x;

  __shared__ float smem[8320];       // A:- B:- C: u/h1 views  D: P_s
  __shared__ float ubar_s[Cn];
  __shared__ unsigned short cyc_s[Tn][3];
  __shared__ float ldsr[4][4];
  __shared__ int   pslot[12];
  __shared__ float red_s[2][4][16];
  __shared__ float sc_s[16];
  __shared__ float par_s[4];
  __shared__ int   pp_s[3];

  // ================= Phase A: autocorr (512 units = b x 16 grp of 4 lags) ==
  {
    const int b   = ws >> 4;
    const int grp = ws & 15;
    const int L0  = 8 + grp * 4;
    const float4* X4 = (const float4*)(x + (size_t)b * Tn * Cn);  // [512][32]

    float acc[4];
#pragma unroll
    for (int i = 0; i < 4; ++i) acc[i] = 0.f;

    for (int it = 0; it < 8; ++it) {
      const int id = it * 256 + tid;
      const int c4 = id & 31;
      const int t0 = (id >> 5) * 8;
      float4 A[8];
#pragma unroll
      for (int j = 0; j < 8; ++j) A[j] = X4[(t0 + j) * 32 + c4];
      float4 R[11];
#pragma unroll
      for (int j = 0; j < 11; ++j) R[j] = X4[((t0 + L0 + j) & 511) * 32 + c4];
#pragma unroll
      for (int g = 0; g < 4; ++g) {
#pragma unroll
        for (int j = 0; j < 8; ++j) {
          const float4 a = A[j];
          const float4 r = R[g + j];
          acc[g] += a.x * r.x + a.y * r.y + a.z * r.z + a.w * r.w;
        }
      }
    }

    const int lane = tid & 63, wv = tid >> 6;
#pragma unroll
    for (int g = 0; g < 4; ++g) {
      float v = acc[g];
#pragma unroll
      for (int m = 32; m > 0; m >>= 1) v += __shfl_xor(v, m, 64);
      if (lane == 0) ldsr[wv][g] = v;
    }
    __syncthreads();
    if (tid < 4) {
      const int li = grp * 4 + tid;
      if (li < NLAG) {
        r_ws[b * NLAG + li] =
            (ldsr[0][tid] + ldsr[1][tid] + ldsr[2][tid] + ldsr[3][tid]) * (1.0f / Cn);
      }
    }
  }
  grid.sync();

  // ================= Phase B: fold (6144 units, 12/block, 2 concurrent) ====
  {
    for (int it2 = 0; it2 < 6; ++it2) {
      const int sub  = tid >> 7;                   // 0 or 1 (half of block)
      const int unit = ws * 12 + it2 * 2 + sub;    // bijective over 0..6143
      const int n = unit >> 6, l = unit & 63;
      const int b = n / 3, kk = n % 3;
      if ((tid & 64) == 0) {                       // first wave of each half
        const int lag = topk_p(r_ws + b * NLAG, tid & 63, kk);
        if ((tid & 63) == 0) pslot[it2 * 2 + sub] = lag;
      }
      __syncthreads();
      const int p    = pslot[it2 * 2 + sub];
      const int ncyc = (Tn + p - 1) / p;
      const int c    = tid & 127;
      float acc = 0.f;
      if (l < ncyc) {
        const float* xb = x + (size_t)b * Tn * Cn;
        const int base = l * p;
        for (int j = 0; j < p; ++j) {
          const int time = base + j;
          const int src  = time < Tn ? time : (2 * (Tn - 1) - time);
          acc += xb[src * Cn + c];
        }
      }
      u[((size_t)n * CYC + l) * Cn + c] = acc * (1.0f / 64.0f);
    }
  }
  grid.sync();

  // ================= Phase C: conv (768 units; XCD k owns n in [12k,12k+12))
  {
    const int j0 = ws & 63;                                    // 0..63
    conv_unit(12 * xcd + (j0 >> 3), j0 & 7, tid,
              u, Wdw, Wpw, gnw, gnb, Wgate, hh, smem, ubar_s);
    if (bid < 256) {   // one active block per CU; XCD-balanced
      const int j1 = 64 + (ws & 31);                           // 64..95
      conv_unit(12 * xcd + (j1 >> 3), j1 & 7, tid,
                u, Wdw, Wpw, gnw, gnb, Wgate, hh, smem, ubar_s);
    }
  }
  grid.sync();

  // ================= Phase D: dot + out (256 units, b x cg of 16 ch) =======
  if (bid < 256) {
    const int unit = xcd * 32 + (ws & 31);   // bijective 0..255
    const int b = unit >> 3, cgp = unit & 7;
    const int c_l = tid & 15;
    const int tg  = tid >> 4;                // 0..15
    const int c   = cgp * 16 + c_l;
    float* P_s = smem;                       // [t*16 + c_l], 8192 floats

    // top-3 + softmax + Gamma (wave 0)
    if (tid < 64) {
      const float* rb = r_ws + b * NLAG;
      float v  = (tid < NLAG) ? rb[tid] : -INFINITY;
      int  idx = tid;
      float vals[3]; int lags[3];
#pragma unroll
      for (int k = 0; k < 3; ++k) {
        float bv = v; int bi = idx;
#pragma unroll
        for (int m = 32; m > 0; m >>= 1) {
          const float ov = __shfl_xor(bv, m, 64);
          const int   oi = __shfl_xor(bi, m, 64);
          if (ov > bv || (ov == bv && oi < bi)) { bv = ov; bi = oi; }
        }
        vals[k] = bv; lags[k] = bi + 8;
        if (idx == bi) v = -INFINITY;
      }
      if (tid == 0) {
        const float m  = vals[0];
        const float e0 = expf(vals[0] - m), e1 = expf(vals[1] - m), e2 = expf(vals[2] - m);
        const float s  = e0 + e1 + e2;
        const float w0 = e0 / s, w1 = e1 / s, w2 = e2 / s;
        pp_s[0] = lags[0]; pp_s[1] = lags[1]; pp_s[2] = lags[2];
        par_s[0] = w0; par_s[1] = w1; par_s[2] = w2;
        const float H  = -(w0 * logf(w0 + 1e-8f) + w1 * logf(w1 + 1e-8f) + w2 * logf(w2 + 1e-8f));
        const float lg = logf(3.0f + 1e-8f) + 1e-8f;
        par_s[3] = fminf(fmaxf(1.0f - H / lg, 0.0f), 1.0f);
      }
    }
    __syncthreads();
    const int p0 = pp_s[0], p1 = pp_s[1], p2 = pp_s[2];
    const float w0 = par_s[0], w1 = par_s[1], w2 = par_s[2];
    const float g  = par_s[3];
    const float sw = w0 + w1 + w2;

    for (int t = tid; t < Tn; t += 256) {
      cyc_s[t][0] = (unsigned short)(t / p0);
      cyc_s[t][1] = (unsigned short)(t / p1);
      cyc_s[t][2] = (unsigned short)(t / p2);
    }
    __syncthreads();

    const float gam = gamma[c];
    const float* xb = x + (size_t)b * Tn * Cn;
    const float* h0 = hh + (size_t)(b * 3 + 0) * CYC * Cn + c;
    const float* h1 = hh + (size_t)(b * 3 + 1) * CYC * Cn + c;
    const float* h2 = hh + (size_t)(b * 3 + 2) * CYC * Cn + c;

    float na = 0.f, da = 0.f;
#pragma unroll 4
    for (int tt = 0; tt < 32; ++tt) {
      const int t = tt * 16 + tg;
      const float xv = xb[t * Cn + c];
      const float dv = gam * (w0 * h0[cyc_s[t][0] * Cn] +
                              w1 * h1[cyc_s[t][1] * Cn] +
                              w2 * h2[cyc_s[t][2] * Cn]);
      const float P = sw * xv + dv;
      P_s[t * 16 + c_l] = P;
      na += (xv - P) * P;
      da += P * P;
    }
    na += __shfl_xor(na, 16, 64); da += __shfl_xor(da, 16, 64);
    na += __shfl_xor(na, 32, 64); da += __shfl_xor(da, 32, 64);
    const int wv_ = tid >> 6;
    if ((tid & 63) < 16) { red_s[0][wv_][c_l] = na; red_s[1][wv_][c_l] = da; }
    __syncthreads();
    if (tid < 16) {
      const float num = red_s[0][0][tid] + red_s[0][1][tid] + red_s[0][2][tid] + red_s[0][3][tid];
      const float den = red_s[1][0][tid] + red_s[1][1][tid] + red_s[1][2][tid] + red_s[1][3][tid] + 1e-6f;
      sc_s[tid] = g * (num / den);
    }
    __syncthreads();
    const float sc = sc_s[c_l];

    float* ob = out + (size_t)b * Tn * Cn;
#pragma unroll 4
    for (int tt = 0; tt < 32; ++tt) {
      const int t = tt * 16 + tg;
      const float xv = xb[t * Cn + c];
      ob[t * Cn + c] = xv - sc * P_s[t * 16 + c_l];
    }
  }
}

// ===========================================================================
// Fallback path (round-2 verified 4-kernel pipeline), used only if the
// cooperative launch is rejected by the runtime / graph capture.
// ===========================================================================
__global__ __launch_bounds__(256) void k_autocorr(const float* __restrict__ x,
    float* __restrict__ r_ws) {
  const int w   = (blockIdx.x & 7) * 32 + (blockIdx.x >> 3);
  const int b   = w >> 3;
  const int grp = w & 7;
  const int L0  = 8 + grp * 8;
  const int tid = threadIdx.x;
  const float4* X4 = (const float4*)(x + (size_t)b * Tn * Cn);

  float acc[8];
#pragma unroll
  for (int i = 0; i < 8; ++i) acc[i] = 0.f;
  for (int it = 0; it < 8; ++it) {
    const int id = it * 256 + tid;
    const int c4 = id & 31;
    const int t0 = (id >> 5) * 8;
    float4 A[8];
#pragma unroll
    for (int j = 0; j < 8; ++j) A[j] = X4[(t0 + j) * 32 + c4];
    float4 R[16];
#pragma unroll
    for (int j = 0; j < 16; ++j) R[j] = X4[((t0 + L0 + j) & 511) * 32 + c4];
#pragma unroll
    for (int g = 0; g < 8; ++g) {
#pragma unroll
      for (int j = 0; j < 8; ++j) {
        const float4 a = A[j];
        const float4 r = R[g + j];
        acc[g] += a.x * r.x + a.y * r.y + a.z * r.z + a.w * r.w;
      }
    }
  }
  __shared__ float lds_r[4][8];
  const int lane = tid & 63, wave = tid >> 6;
#pragma unroll
  for (int g = 0; g < 8; ++g) {
    float v = acc[g];
#pragma unroll
    for (int m = 32; m > 0; m >>= 1) v += __shfl_xor(v, m, 64);
    if (lane == 0) lds_r[wave][g] = v;
  }
  __syncthreads();
  if (tid < 8) {
    const int li = grp * 8 + tid;
    if (li < NLAG)
      r_ws[b * NLAG + li] =
          (lds_r[0][tid] + lds_r[1][tid] + lds_r[2][tid] + lds_r[3][tid]) * (1.0f / Cn);
  }
}

__global__ __launch_bounds__(128) void k_fold_u(const float* __restrict__ x,
    const float* __restrict__ r_ws, float* __restrict__ u) {
  const int bid = blockIdx.x;
  const int w = (bid & 7) * 768 + (bid >> 3);
  const int n = w >> 6, l = w & 63;
  const int b = n / 3, kk = n % 3;
  const int tid = threadIdx.x;
  __shared__ int p_sh;
  if (tid < 64) {
    const int lag = topk_p(r_ws + b * NLAG, tid, kk);
    if (tid == 0) p_sh = lag;
  }
  __syncthreads();
  const int p = p_sh;
  const int ncyc = (Tn + p - 1) / p;
  float acc = 0.f;
  if (l < ncyc) {
    const float* xb = x + (size_t)b * Tn * Cn;
    const int base = l * p;
    for (int j = 0; j < p; ++j) {
      const int time = base + j;
      const int src  = time < Tn ? time : (2 * (Tn - 1) - time);
      acc += xb[src * Cn + tid];
    }
  }
  u[((size_t)n * CYC + l) * Cn + tid] = acc * (1.0f / 64.0f);
}

__global__ __launch_bounds__(256) void k_conv(
    const float* __restrict__ u, const float* __restrict__ Wdw,
    const float* __restrict__ Wpw, const float* __restrict__ gnw,
    const float* __restrict__ gnb, const float* __restrict__ Wgate,
    float* __restrict__ hh) {
  const int bid = blockIdx.x;
  const int w = (bid & 7) * 96 + (bid >> 3);
  const int n = w >> 3, og = w & 7;
  __shared__ float smem[8320];
  __shared__ float ubar_s[Cn];
  conv_unit(n, og, threadIdx.x, u, Wdw, Wpw, gnw, gnb, Wgate, hh, smem, ubar_s);
}

__global__ __launch_bounds__(256) void k_dot_out(
    const float* __restrict__ x, const float* __restrict__ hh,
    const float* __restrict__ r_ws, const float* __restrict__ gamma,
    float* __restrict__ out) {
  const int bid = blockIdx.x;
  const int w = (bid & 7) * 32 + (bid >> 3);
  const int b = w >> 3, cg = w & 7;
  const int tid = threadIdx.x;
  const int c_l = tid & 15;
  const int tg  = tid >> 4;
  const int c   = cg * 16 + c_l;

  __shared__ float P_s[Tn * 16];
  __shared__ unsigned short cyc_s[Tn][3];
  __shared__ float params[4];
  __shared__ int   pp[3];
  __shared__ float red[2][4][16];
  __shared__ float sc_s[16];

  if (tid < 64) {
    const float* rb = r_ws + b * NLAG;
    float v  = (tid < NLAG) ? rb[tid] : -INFINITY;
    int  idx = tid;
    float vals[3]; int lags[3];
#pragma unroll
    for (int k = 0; k < 3; ++k) {
      float bv = v; int bi = idx;
#pragma unroll
      for (int m = 32; m > 0; m >>= 1) {
        const float ov = __shfl_xor(bv, m, 64);
        const int   oi = __shfl_xor(bi, m, 64);
        if (ov > bv || (ov == bv && oi < bi)) { bv = ov; bi = oi; }
      }
      vals[k] = bv; lags[k] = bi + 8;
      if (idx == bi) v = -INFINITY;
    }
    if (tid == 0) {
      const float m  = vals[0];
      const float e0 = expf(vals[0] - m), e1 = expf(vals[1] - m), e2 = expf(vals[2] - m);
      const float s  = e0 + e1 + e2;
      const float w0 = e0 / s, w1 = e1 / s, w2 = e2 / s;
      pp[0] = lags[0]; pp[1] = lags[1]; pp[2] = lags[2];
      params[0] = w0; params[1] = w1; params[2] = w2;
      const float H  = -(w0 * logf(w0 + 1e-8f) + w1 * logf(w1 + 1e-8f) + w2 * logf(w2 + 1e-8f));
      const float lg = logf(3.0f + 1e-8f) + 1e-8f;
      params[3] = fminf(fmaxf(1.0f - H / lg, 0.0f), 1.0f);
    }
  }
  __syncthreads();
  const int p0 = pp[0], p1 = pp[1], p2 = pp[2];
  const float w0 = params[0], w1 = params[1], w2 = params[2];
  const float g  = params[3];
  const float sw = w0 + w1 + w2;

  for (int t = tid; t < Tn; t += 256) {
    cyc_s[t][0] = (unsigned short)(t / p0);
    cyc_s[t][1] = (unsigned short)(t / p1);
    cyc_s[t][2] = (unsigned short)(t / p2);
  }
  __syncthreads();

  const float gam = gamma[c];
  const float* xb = x + (size_t)b * Tn * Cn;
  const float* h0 = hh + (size_t)(b * 3 + 0) * CYC * Cn + c;
  const float* h1 = hh + (size_t)(b * 3 + 1) * CYC * Cn + c;
  const float* h2 = hh + (size_t)(b * 3 + 2) * CYC * Cn + c;

  float na = 0.f, da = 0.f;
#pragma unroll 4
  for (int tt = 0; tt < 32; ++tt) {
    const int t = tt * 16 + tg;
    const float xv = xb[t * Cn + c];
    const float dv = gam * (w0 * h0[cyc_s[t][0] * Cn] +
                            w1 * h1[cyc_s[t][1] * Cn] +
                            w2 * h2[cyc_s[t][2] * Cn]);
    const float P = sw * xv + dv;
    P_s[t * 16 + c_l] = P;
    na += (xv - P) * P;
    da += P * P;
  }
  na += __shfl_xor(na, 16, 64); da += __shfl_xor(da, 16, 64);
  na += __shfl_xor(na, 32, 64); da += __shfl_xor(da, 32, 64);
  const int wv_ = tid >> 6;
  if ((tid & 63) < 16) { red[0][wv_][c_l] = na; red[1][wv_][c_l] = da; }
  __syncthreads();
  if (tid < 16) {
    const float num = red[0][0][tid] + red[0][1][tid] + red[0][2][tid] + red[0][3][tid];
    const float den = red[1][0][tid] + red[1][1][tid] + red[1][2][tid] + red[1][3][tid] + 1e-6f;
    sc_s[tid] = g * (num / den);
  }
  __syncthreads();
  const float sc = sc_s[c_l];

  float* ob = out + (size_t)b * Tn * Cn;
#pragma unroll 4
  for (int tt = 0; tt < 32; ++tt) {
    const int t = tt * 16 + tg;
    const float xv = xb[t * Cn + c];
    ob[t * Cn + c] = xv - sc * P_s[t * 16 + c_l];
  }
}

// ---------------------------------------------------------------------------
extern "C" void kernel_launch(void* const* d_in, const int* in_sizes, int n_in,
                              void* d_out, int out_size, void* d_ws, size_t ws_size,
                              hipStream_t stream) {
  const float* x     = (const float*)d_in[0];
  const float* Wdw   = (const float*)d_in[1];
  const float* Wpw   = (const float*)d_in[2];
  const float* gnw   = (const float*)d_in[3];
  const float* gnb   = (const float*)d_in[4];
  const float* Wgate = (const float*)d_in[5];
  const float* gamma = (const float*)d_in[6];
  float* out = (float*)d_out;

  char* ws = (char*)d_ws;
  float* r_ws = (float*)ws;                       // 32*57 floats
  float* u    = (float*)(ws + 8192);              // 96*64*128 floats (3 MB)
  float* hh   = (float*)(ws + 8192 + 3145728);    // 3 MB

  void* args[] = {
    (void*)&x, (void*)&Wdw, (void*)&Wpw, (void*)&gnw, (void*)&gnb,
    (void*)&Wgate, (void*)&gamma, (void*)&r_ws, (void*)&u, (void*)&hh,
    (void*)&out
  };
  hipError_t e = hipLaunchCooperativeKernel((const void*)mega, dim3(512),
                                            dim3(256), args, 0, stream);
  if (e != hipSuccess) {
    (void)hipGetLastError();   // clear sticky error
    k_autocorr<<<Bn * 8, 256, 0, stream>>>(x, r_ws);
    k_fold_u<<<6144, 128, 0, stream>>>(x, r_ws, u);
    k_conv<<<768, 256, 0, stream>>>(u, Wdw, Wpw, gnw, gnb, Wgate, hh);
    k_dot_out<<<256, 256, 0, stream>>>(x, hh, r_ws, gamma, out);
  }
}

// Round 5
// 133.879 us; speedup vs baseline: 2.8812x; 2.8812x over previous
//
#include <hip/hip_runtime.h>
#include <math.h>

// Problem constants
static constexpr int Bn   = 32;
static constexpr int Tn   = 512;
static constexpr int Cn   = 128;
static constexpr int NLAG = 57;   // lags 8..64 inclusive
static constexpr int CYC  = 64;   // CYC_MAX

// ---------------------------------------------------------------------------
// Wave-parallel top-(kk+1) argmax over r_ws[b] (57 lags). lane = tid 0..63.
// Matches lax.top_k tie-break (smallest index wins on equal values).
// ---------------------------------------------------------------------------
__device__ __forceinline__ int topk_p(const float* __restrict__ rb,
                                      int lane, int kk) {
  float v  = (lane < NLAG) ? rb[lane] : -INFINITY;
  int  idx = lane;
  int  lag = 8;
#pragma unroll
  for (int k = 0; k < 3; ++k) {
    if (k > kk) break;
    float bv = v; int bi = idx;
#pragma unroll
    for (int m = 32; m > 0; m >>= 1) {
      const float ov = __shfl_xor(bv, m, 64);
      const int   oi = __shfl_xor(bi, m, 64);
      if (ov > bv || (ov == bv && oi < bi)) { bv = ov; bi = oi; }
    }
    lag = bi + 8;
    if (idx == bi) v = -INFINITY;
  }
  return lag;
}

// ---------------------------------------------------------------------------
// K1: circular autocorrelation. Logical work (b, lag-group of 8).
// XCD swizzle: each XCD owns 4 consecutive b (1MB working set < 4MB L2).
// (verified round-2 version, unchanged)
// ---------------------------------------------------------------------------
__global__ __launch_bounds__(256) void k_autocorr(const float* __restrict__ x,
    float* __restrict__ r_ws) {
  const int w   = (blockIdx.x & 7) * 32 + (blockIdx.x >> 3);  // bijective 0..255
  const int b   = w >> 3;
  const int grp = w & 7;
  const int L0  = 8 + grp * 8;
  const int tid = threadIdx.x;
  const float4* X4 = (const float4*)(x + (size_t)b * Tn * Cn);  // [512][32]

  float acc[8];
#pragma unroll
  for (int i = 0; i < 8; ++i) acc[i] = 0.f;

  for (int it = 0; it < 8; ++it) {
    const int id = it * 256 + tid;
    const int c4 = id & 31;
    const int t0 = (id >> 5) * 8;
    float4 A[8];
#pragma unroll
    for (int j = 0; j < 8; ++j) A[j] = X4[(t0 + j) * 32 + c4];
    float4 R[16];
#pragma unroll
    for (int j = 0; j < 16; ++j) R[j] = X4[((t0 + L0 + j) & 511) * 32 + c4];
#pragma unroll
    for (int g = 0; g < 8; ++g) {
#pragma unroll
      for (int j = 0; j < 8; ++j) {
        const float4 a = A[j];
        const float4 r = R[g + j];
        acc[g] += a.x * r.x + a.y * r.y + a.z * r.z + a.w * r.w;
      }
    }
  }

  __shared__ float lds_r[4][8];
  const int lane = tid & 63, wave = tid >> 6;
#pragma unroll
  for (int g = 0; g < 8; ++g) {
    float v = acc[g];
#pragma unroll
    for (int m = 32; m > 0; m >>= 1) v += __shfl_xor(v, m, 64);
    if (lane == 0) lds_r[wave][g] = v;
  }
  __syncthreads();
  if (tid < 8) {
    const int li = grp * 8 + tid;
    if (li < NLAG) {
      r_ws[b * NLAG + li] =
          (lds_r[0][tid] + lds_r[1][tid] + lds_r[2][tid] + lds_r[3][tid]) * (1.0f / Cn);
    }
  }
}

// ---------------------------------------------------------------------------
// K2: fold, float4. Block per (n, l): 6144 blocks x 128 threads.
// Lanes: c4 = tid&31 (32 float4 across C), r = tid>>5 (4 j-residues).
// 4x fewer load instructions and 4x shorter per-thread load chain vs scalar.
// XCD swizzle unchanged.
// ---------------------------------------------------------------------------
__global__ __launch_bounds__(128) void k_fold_u(const float* __restrict__ x,
    const float* __restrict__ r_ws, float* __restrict__ u) {
  const int bid = blockIdx.x;                       // 0..6143
  const int w = (bid & 7) * 768 + (bid >> 3);       // bijective
  const int n = w >> 6, l = w & 63;
  const int b = n / 3, kk = n % 3;
  const int tid = threadIdx.x;

  __shared__ int p_sh;
  __shared__ float4 fr[32];
  if (tid < 64) {
    const int lag = topk_p(r_ws + b * NLAG, tid, kk);
    if (tid == 0) p_sh = lag;
  }
  __syncthreads();
  const int p    = p_sh;
  const int ncyc = (Tn + p - 1) / p;
  const int c4   = tid & 31;
  const int r    = tid >> 5;       // 0..3

  float4 acc = {0.f, 0.f, 0.f, 0.f};
  if (l < ncyc) {
    const float4* xb4 = (const float4*)(x + (size_t)b * Tn * Cn);  // [512][32]
    const int base = l * p;
    for (int j = r; j < p; j += 4) {
      const int time = base + j;
      const int src  = time < Tn ? time : (2 * (Tn - 1) - time);
      const float4 v = xb4[src * 32 + c4];
      acc.x += v.x; acc.y += v.y; acc.z += v.z; acc.w += v.w;
    }
  }
  // combine residue pairs within each wave (r0+r1 in wave0, r2+r3 in wave1)
  acc.x += __shfl_xor(acc.x, 32, 64);
  acc.y += __shfl_xor(acc.y, 32, 64);
  acc.z += __shfl_xor(acc.z, 32, 64);
  acc.w += __shfl_xor(acc.w, 32, 64);
  if (tid >= 64 && (tid & 63) < 32) fr[c4] = acc;   // wave1 publishes r2+r3
  __syncthreads();
  if (tid < 32) {
    const float4 o = fr[c4];
    float4 res;
    res.x = (acc.x + o.x) * (1.0f / 64.0f);
    res.y = (acc.y + o.y) * (1.0f / 64.0f);
    res.z = (acc.z + o.z) * (1.0f / 64.0f);
    res.w = (acc.w + o.w) * (1.0f / 64.0f);
    ((float4*)u)[((size_t)n * CYC + l) * 32 + c4] = res;
  }
}

// ---------------------------------------------------------------------------
// K3: conv chain (dw + pw + GN + gelu + gate). Verified round-2 version.
// Grid: 768 blocks (n=96, og=8), 256 threads = 4 waves.
// LDS: one 8320-float buffer: u-view [64][129], then h1-view [128][65].
// ---------------------------------------------------------------------------
__global__ __launch_bounds__(256) void k_conv(
    const float* __restrict__ u, const float* __restrict__ Wdw,
    const float* __restrict__ Wpw, const float* __restrict__ gnw,
    const float* __restrict__ gnb, const float* __restrict__ Wgate,
    float* __restrict__ hh) {
  const int bid = blockIdx.x;                      // 0..767
  const int w = (bid & 7) * 96 + (bid >> 3);       // bijective
  const int n = w >> 3, og = w & 7;
  const int tid  = threadIdx.x;
  const int l    = tid & 63;
  const int wq   = __builtin_amdgcn_readfirstlane(tid >> 6);

  __shared__ float smem[8320];     // u-view [l][129]; h1-view [c][65]
  __shared__ float ubar_s[Cn];

  // stage u[n] (32KB): float4 global loads, scalar LDS writes into pad-129
  {
    const float4* u4 = (const float4*)(u + (size_t)n * CYC * Cn);
#pragma unroll
    for (int i = 0; i < 8; ++i) {
      const int idx4 = i * 256 + tid;      // 0..2047
      const float4 v = u4[idx4];
      const int ll = idx4 >> 5;
      const int cc = (idx4 & 31) << 2;
      float* d = smem + ll * 129 + cc;
      d[0] = v.x; d[1] = v.y; d[2] = v.z; d[3] = v.w;
    }
  }
  __syncthreads();

  // ubar[c] = mean over l (threads 0..127); stride-129 columns conflict-free
  if (tid < Cn) {
    float s = 0.f;
    for (int ll = 0; ll < CYC; ++ll) s += smem[ll * 129 + tid];
    ubar_s[tid] = s * (1.0f / CYC);
  }

  // depthwise conv -> registers: thread (l, wq) covers c = wq*32 .. +32
  float hreg[32];
  {
    const int c0 = wq * 32;
#pragma unroll
    for (int i = 0; i < 32; ++i) {
      const int c = c0 + i;
      float s = 0.f;
#pragma unroll
      for (int k = 0; k < 9; ++k) {
        const int ll = l + k - 4;
        if (ll >= 0 && ll < CYC) s += smem[ll * 129 + c] * Wdw[c * 9 + k];
      }
      hreg[i] = s;
    }
  }
  __syncthreads();   // all su reads done; ubar_s visible

  // gates: each wave computes its own 4 outputs; 16 lane-groups x 8 channels
  float gi[4];
  {
    const int ol   = l & 3;
    const int part = l >> 2;               // 0..15
    const int o    = og * 16 + wq * 4 + ol;
    float z = 0.f;
    const float* wg = Wgate + (size_t)o * Cn + part * 8;
    const float* ub = ubar_s + part * 8;
#pragma unroll
    for (int cc = 0; cc < 8; ++cc) z += wg[cc] * ub[cc];
    z += __shfl_xor(z, 4, 64);
    z += __shfl_xor(z, 8, 64);
    z += __shfl_xor(z, 16, 64);
    z += __shfl_xor(z, 32, 64);
    const float sig = 1.0f / (1.0f + expf(-z));
#pragma unroll
    for (int i = 0; i < 4; ++i) gi[i] = __shfl(sig, i, 64);
  }

  // overwrite LDS with h1-view [c][65]
  {
    const int c0 = wq * 32;
#pragma unroll
    for (int i = 0; i < 32; ++i) smem[(c0 + i) * 65 + l] = hreg[i];
  }
  __syncthreads();

  // pointwise: 4 outputs per wave
  const int o4 = og * 16 + wq * 4;
  float acc[4];
#pragma unroll
  for (int i = 0; i < 4; ++i) acc[i] = 0.f;
  const float* wb = Wpw + (size_t)o4 * Cn;
  for (int c = 0; c < Cn; ++c) {
    const float hv = smem[c * 65 + l];
#pragma unroll
    for (int i = 0; i < 4; ++i) acc[i] = fmaf(wb[i * Cn + c], hv, acc[i]);
  }

  // GroupNorm: this wave's 4 o == exactly one GN group (4 ch x 64 l)
  float s1 = acc[0] + acc[1] + acc[2] + acc[3];
  float s2 = acc[0]*acc[0] + acc[1]*acc[1] + acc[2]*acc[2] + acc[3]*acc[3];
#pragma unroll
  for (int m = 32; m > 0; m >>= 1) {
    s1 += __shfl_xor(s1, m, 64);
    s2 += __shfl_xor(s2, m, 64);
  }
  const float mean = s1 * (1.0f / 256.0f);
  const float var  = s2 * (1.0f / 256.0f) - mean * mean;
  const float rstd = rsqrtf(var + 1e-5f);

  float4 res;
  float* rp = (float*)&res;
#pragma unroll
  for (int i = 0; i < 4; ++i) {
    const int o = o4 + i;
    float h = (acc[i] - mean) * rstd;
    h = h * gnw[o] + gnb[o];
    h = 0.5f * h * (1.0f + erff(h * 0.70710678118654752440f));
    rp[i] = h * gi[i];
  }
  *(float4*)(hh + (size_t)n * CYC * Cn + (size_t)l * Cn + o4) = res;
}

// ---------------------------------------------------------------------------
// K4: fused dot + out, float4. 256 blocks (b=32, cg=8), 256 threads:
// c4 = tid&3 (4 float4 = 16 channels), tg = tid>>2 (64 t-groups x 8 t).
// All global loads/stores are float4 (4x fewer memory instructions).
// num/den stay per-channel (float4 accumulators), reduced over tg via
// xor-4..32 shuffles + cross-wave LDS. P_s float4 is 2-way aliased = free.
// XCD swizzle: 4 consecutive b per XCD.
// ---------------------------------------------------------------------------
__global__ __launch_bounds__(256) void k_dot_out(
    const float* __restrict__ x, const float* __restrict__ hh,
    const float* __restrict__ r_ws, const float* __restrict__ gamma,
    float* __restrict__ out) {
  const int bid = blockIdx.x;                     // 0..255
  const int w = (bid & 7) * 32 + (bid >> 3);      // bijective
  const int b = w >> 3, cg = w & 7;
  const int tid = threadIdx.x;
  const int c4  = tid & 3;          // which float4 of the 16-channel slice
  const int tg  = tid >> 2;         // 0..63
  const int cw  = cg * 4 + c4;      // float4 column index 0..31

  __shared__ float4 P_s[Tn * 4];           // [t*4 + c4], 32 KB
  __shared__ unsigned short cyc_s[Tn][3];
  __shared__ float params[4];              // w0,w1,w2,g
  __shared__ int   pp[3];
  __shared__ float4 redn[4][4], redd[4][4];
  __shared__ float4 sc_s[4];

  // ---- wave-parallel top-3 + softmax + Gamma ----
  if (tid < 64) {
    const float* rb = r_ws + b * NLAG;
    float v  = (tid < NLAG) ? rb[tid] : -INFINITY;
    int  idx = tid;
    float vals[3]; int lags[3];
#pragma unroll
    for (int k = 0; k < 3; ++k) {
      float bv = v; int bi = idx;
#pragma unroll
      for (int m = 32; m > 0; m >>= 1) {
        const float ov = __shfl_xor(bv, m, 64);
        const int   oi = __shfl_xor(bi, m, 64);
        if (ov > bv || (ov == bv && oi < bi)) { bv = ov; bi = oi; }
      }
      vals[k] = bv; lags[k] = bi + 8;
      if (idx == bi) v = -INFINITY;
    }
    if (tid == 0) {
      const float m  = vals[0];
      const float e0 = expf(vals[0] - m), e1 = expf(vals[1] - m), e2 = expf(vals[2] - m);
      const float s  = e0 + e1 + e2;
      const float w0 = e0 / s, w1 = e1 / s, w2 = e2 / s;
      pp[0] = lags[0]; pp[1] = lags[1]; pp[2] = lags[2];
      params[0] = w0; params[1] = w1; params[2] = w2;
      const float H  = -(w0 * logf(w0 + 1e-8f) + w1 * logf(w1 + 1e-8f) + w2 * logf(w2 + 1e-8f));
      const float lg = logf(3.0f + 1e-8f) + 1e-8f;
      params[3] = fminf(fmaxf(1.0f - H / lg, 0.0f), 1.0f);
    }
  }
  __syncthreads();
  const int p0 = pp[0], p1 = pp[1], p2 = pp[2];
  const float w0 = params[0], w1 = params[1], w2 = params[2];
  const float g  = params[3];
  const float sw = w0 + w1 + w2;

  for (int t = tid; t < Tn; t += 256) {
    cyc_s[t][0] = (unsigned short)(t / p0);
    cyc_s[t][1] = (unsigned short)(t / p1);
    cyc_s[t][2] = (unsigned short)(t / p2);
  }
  __syncthreads();

  const float4 gam = ((const float4*)gamma)[cw];
  const float4* xb4 = (const float4*)(x + (size_t)b * Tn * Cn);          // [512][32]
  const float4* h04 = (const float4*)(hh + (size_t)(b * 3 + 0) * CYC * Cn);
  const float4* h14 = (const float4*)(hh + (size_t)(b * 3 + 1) * CYC * Cn);
  const float4* h24 = (const float4*)(hh + (size_t)(b * 3 + 2) * CYC * Cn);

  float4 na = {0.f, 0.f, 0.f, 0.f}, da = {0.f, 0.f, 0.f, 0.f};
#pragma unroll
  for (int tt = 0; tt < 8; ++tt) {
    const int t = tt * 64 + tg;
    const float4 xv = xb4[t * 32 + cw];
    const float4 a0 = h04[cyc_s[t][0] * 32 + cw];
    const float4 a1 = h14[cyc_s[t][1] * 32 + cw];
    const float4 a2 = h24[cyc_s[t][2] * 32 + cw];
    float4 P;
    P.x = sw * xv.x + gam.x * (w0 * a0.x + w1 * a1.x + w2 * a2.x);
    P.y = sw * xv.y + gam.y * (w0 * a0.y + w1 * a1.y + w2 * a2.y);
    P.z = sw * xv.z + gam.z * (w0 * a0.z + w1 * a1.z + w2 * a2.z);
    P.w = sw * xv.w + gam.w * (w0 * a0.w + w1 * a1.w + w2 * a2.w);
    P_s[t * 4 + c4] = P;
    na.x += (xv.x - P.x) * P.x;  da.x += P.x * P.x;
    na.y += (xv.y - P.y) * P.y;  da.y += P.y * P.y;
    na.z += (xv.z - P.z) * P.z;  da.z += P.z * P.z;
    na.w += (xv.w - P.w) * P.w;  da.w += P.w * P.w;
  }
  // reduce over the 16 tg within each wave (lane strides 4,8,16,32)
#pragma unroll
  for (int m = 4; m <= 32; m <<= 1) {
    na.x += __shfl_xor(na.x, m, 64);  da.x += __shfl_xor(da.x, m, 64);
    na.y += __shfl_xor(na.y, m, 64);  da.y += __shfl_xor(da.y, m, 64);
    na.z += __shfl_xor(na.z, m, 64);  da.z += __shfl_xor(da.z, m, 64);
    na.w += __shfl_xor(na.w, m, 64);  da.w += __shfl_xor(da.w, m, 64);
  }
  const int wv_ = tid >> 6;
  if ((tid & 63) < 4) { redn[wv_][c4] = na; redd[wv_][c4] = da; }
  __syncthreads();
  if (tid < 4) {
    float4 n4, d4, s;
    n4.x = redn[0][tid].x + redn[1][tid].x + redn[2][tid].x + redn[3][tid].x;
    n4.y = redn[0][tid].y + redn[1][tid].y + redn[2][tid].y + redn[3][tid].y;
    n4.z = redn[0][tid].z + redn[1][tid].z + redn[2][tid].z + redn[3][tid].z;
    n4.w = redn[0][tid].w + redn[1][tid].w + redn[2][tid].w + redn[3][tid].w;
    d4.x = redd[0][tid].x + redd[1][tid].x + redd[2][tid].x + redd[3][tid].x + 1e-6f;
    d4.y = redd[0][tid].y + redd[1][tid].y + redd[2][tid].y + redd[3][tid].y + 1e-6f;
    d4.z = redd[0][tid].z + redd[1][tid].z + redd[2][tid].z + redd[3][tid].z + 1e-6f;
    d4.w = redd[0][tid].w + redd[1][tid].w + redd[2][tid].w + redd[3][tid].w + 1e-6f;
    s.x = g * (n4.x / d4.x);
    s.y = g * (n4.y / d4.y);
    s.z = g * (n4.z / d4.z);
    s.w = g * (n4.w / d4.w);
    sc_s[tid] = s;
  }
  __syncthreads();
  const float4 sc = sc_s[c4];

  float4* ob4 = (float4*)(out + (size_t)b * Tn * Cn);
#pragma unroll
  for (int tt = 0; tt < 8; ++tt) {
    const int t = tt * 64 + tg;
    const float4 xv = xb4[t * 32 + cw];
    const float4 P  = P_s[t * 4 + c4];
    float4 o;
    o.x = xv.x - sc.x * P.x;
    o.y = xv.y - sc.y * P.y;
    o.z = xv.z - sc.z * P.z;
    o.w = xv.w - sc.w * P.w;
    ob4[t * 32 + cw] = o;
  }
}

// ---------------------------------------------------------------------------
extern "C" void kernel_launch(void* const* d_in, const int* in_sizes, int n_in,
                              void* d_out, int out_size, void* d_ws, size_t ws_size,
                              hipStream_t stream) {
  const float* x     = (const float*)d_in[0];
  const float* Wdw   = (const float*)d_in[1];
  const float* Wpw   = (const float*)d_in[2];
  const float* gnw   = (const float*)d_in[3];
  const float* gnb   = (const float*)d_in[4];
  const float* Wgate = (const float*)d_in[5];
  const float* gamma = (const float*)d_in[6];
  float* out = (float*)d_out;

  char* ws = (char*)d_ws;
  float* r_ws = (float*)ws;                       // 32*57 floats
  float* u    = (float*)(ws + 8192);              // 96*64*128 floats (3 MB)
  float* hh   = (float*)(ws + 8192 + 3145728);    // 3 MB

  k_autocorr<<<Bn * 8, 256, 0, stream>>>(x, r_ws);
  k_fold_u<<<6144, 128, 0, stream>>>(x, r_ws, u);
  k_conv<<<768, 256, 0, stream>>>(u, Wdw, Wpw, gnw, gnb, Wgate, hh);
  k_dot_out<<<256, 256, 0, stream>>>(x, hh, r_ws, gamma, out);
}